// Round 1
// baseline (288.899 us; speedup 1.0000x reference)
//
#include <hip/hip_runtime.h>
#include <hip/hip_bf16.h>

#define BB 32
#define HH 56
#define WW 56
#define CC 256
#define NPIX (BB*HH*WW)   // 100352
#define EPS 1e-5f

// ws layout:
//   float stats[512]   : byte 0      (sum[256], sumsq[256])
//   float ss[512]      : byte 2048   (scale[256], shift[256])
//   bf16  y[B*H*W*256] : byte 4096   (51.4 MB)

__global__ void k0_zero(float* stats) {
    stats[threadIdx.x] = 0.f;
}

__global__ __launch_bounds__(256) void k1_conv(
    const float* __restrict__ x, const float* __restrict__ wgt,
    __hip_bfloat16* __restrict__ y, float* __restrict__ stats)
{
    __shared__ float xs[3*58*64];   // [row][col(-1..56)][ci] 43.5 KB
    __shared__ float bsum[64];
    __shared__ float bsq[64];

    const int Q  = blockIdx.x;          // channel quarter (64 channels)
    const int h  = blockIdx.y;
    const int b  = blockIdx.z;
    const int t  = threadIdx.x;
    const int cl = t & 63;              // local output channel
    const int q  = t >> 6;              // pixel quarter (14 px each)
    const int cbase = Q * 64;
    const int c  = cbase + cl;          // global output channel

    if (t < 64) { bsum[t] = 0.f; bsq[t] = 0.f; }

    // ---- stage input tile: rows h-1..h+1, cols -1..56, channels [cbase, cbase+64)
    for (int i = t; i < 3*58*16; i += 256) {
        int ci4  = i & 15;
        int rc   = i >> 4;
        int row  = rc / 58;
        int col  = rc - row*58;
        int hh   = h - 1 + row;
        int wcol = col - 1;
        float4 v = make_float4(0.f, 0.f, 0.f, 0.f);
        if ((unsigned)hh < HH && (unsigned)wcol < WW) {
            v = *(const float4*)(x + (((size_t)(b*HH + hh)*WW + wcol)*CC + cbase + ci4*4));
        }
        *(float4*)(xs + (row*58 + col)*64 + ci4*4) = v;
    }

    // ---- weights into registers: wgt[((kh*3+kw)*8+ci)*256 + c], coalesced over c
    float wr[9][8];
    #pragma unroll
    for (int k = 0; k < 9; ++k)
        #pragma unroll
        for (int ci = 0; ci < 8; ++ci)
            wr[k][ci] = wgt[(k*8 + ci)*CC + c];

    __syncthreads();

    const int gofs = (cl >> 3) * 8;     // input-channel offset of this group in tile
    const int w0   = q * 14;

    // sliding register window: [row][slot][ci], slot = (xs col) relative mod 3
    float xw[3][3][8];
    #pragma unroll
    for (int r = 0; r < 3; ++r) {
        #pragma unroll
        for (int s = 0; s < 2; ++s) {
            const float* p = xs + (r*58 + w0 + s)*64 + gofs;
            float4 u = *(const float4*)p;
            float4 v = *(const float4*)(p + 4);
            xw[r][s][0]=u.x; xw[r][s][1]=u.y; xw[r][s][2]=u.z; xw[r][s][3]=u.w;
            xw[r][s][4]=v.x; xw[r][s][5]=v.y; xw[r][s][6]=v.z; xw[r][s][7]=v.w;
        }
    }

    float lsum = 0.f, lsq = 0.f;
    const size_t ybase = ((size_t)(b*HH + h)*WW)*CC;

    #pragma unroll
    for (int px = 0; px < 14; ++px) {
        // load next column (xs col = w0+px+2) into slot (px+2)%3
        const int snew = (px + 2) % 3;
        #pragma unroll
        for (int r = 0; r < 3; ++r) {
            const float* p = xs + (r*58 + w0 + px + 2)*64 + gofs;
            float4 u = *(const float4*)p;
            float4 v = *(const float4*)(p + 4);
            xw[r][snew][0]=u.x; xw[r][snew][1]=u.y; xw[r][snew][2]=u.z; xw[r][snew][3]=u.w;
            xw[r][snew][4]=v.x; xw[r][snew][5]=v.y; xw[r][snew][6]=v.z; xw[r][snew][7]=v.w;
        }
        float a0 = 0.f, a1 = 0.f, a2 = 0.f;   // per-row accumulators (break dep chain)
        #pragma unroll
        for (int kw = 0; kw < 3; ++kw) {
            const int s = (px + kw) % 3;       // compile-time after unroll
            #pragma unroll
            for (int ci = 0; ci < 8; ++ci) {
                a0 += xw[0][s][ci] * wr[0*3+kw][ci];
                a1 += xw[1][s][ci] * wr[1*3+kw][ci];
                a2 += xw[2][s][ci] * wr[2*3+kw][ci];
            }
        }
        float acc = a0 + a1 + a2;
        y[ybase + (size_t)(w0 + px)*CC + c] = __float2bfloat16(acc);
        lsum += acc;
        lsq  += acc * acc;
    }

    atomicAdd(&bsum[cl], lsum);
    atomicAdd(&bsq[cl],  lsq);
    __syncthreads();
    if (t < 64) {
        atomicAdd(&stats[cbase + t],       bsum[t]);
        atomicAdd(&stats[256 + cbase + t], bsq[t]);
    }
}

__global__ void k2_finalize(const float* __restrict__ stats,
                            const float* __restrict__ gamma,
                            const float* __restrict__ beta,
                            float* __restrict__ ss)
{
    int cidx = threadIdx.x;
    float n    = (float)NPIX;
    float mean = stats[cidx] / n;
    float var  = stats[256 + cidx] / n - mean * mean;
    float scale = gamma[cidx] * rsqrtf(var + EPS);
    ss[cidx]       = scale;
    ss[256 + cidx] = beta[cidx] - mean * scale;   // bias cancels under BN
}

__global__ __launch_bounds__(256) void k3_norm(
    const __hip_bfloat16* __restrict__ y, const float* __restrict__ ss,
    float* __restrict__ out)
{
    __shared__ float ls[512];
    const int t = threadIdx.x;
    ls[t]       = ss[t];
    ls[t + 256] = ss[t + 256];
    __syncthreads();

    const size_t gid = (size_t)blockIdx.x * 256 + t;   // 8 elements per thread
    uint4 d = ((const uint4*)y)[gid];
    const int c0 = (int)((gid & 31) * 8);

    float f0 = __uint_as_float((d.x & 0xffffu) << 16);
    float f1 = __uint_as_float(d.x & 0xffff0000u);
    float f2 = __uint_as_float((d.y & 0xffffu) << 16);
    float f3 = __uint_as_float(d.y & 0xffff0000u);
    float f4 = __uint_as_float((d.z & 0xffffu) << 16);
    float f5 = __uint_as_float(d.z & 0xffff0000u);
    float f6 = __uint_as_float((d.w & 0xffffu) << 16);
    float f7 = __uint_as_float(d.w & 0xffff0000u);

    float4 o0, o1;
    o0.x = fmaxf(0.f, f0 * ls[c0+0] + ls[256 + c0+0]);
    o0.y = fmaxf(0.f, f1 * ls[c0+1] + ls[256 + c0+1]);
    o0.z = fmaxf(0.f, f2 * ls[c0+2] + ls[256 + c0+2]);
    o0.w = fmaxf(0.f, f3 * ls[c0+3] + ls[256 + c0+3]);
    o1.x = fmaxf(0.f, f4 * ls[c0+4] + ls[256 + c0+4]);
    o1.y = fmaxf(0.f, f5 * ls[c0+5] + ls[256 + c0+5]);
    o1.z = fmaxf(0.f, f6 * ls[c0+6] + ls[256 + c0+6]);
    o1.w = fmaxf(0.f, f7 * ls[c0+7] + ls[256 + c0+7]);

    float4* op = (float4*)out;
    op[gid*2]     = o0;
    op[gid*2 + 1] = o1;
}

extern "C" void kernel_launch(void* const* d_in, const int* in_sizes, int n_in,
                              void* d_out, int out_size, void* d_ws, size_t ws_size,
                              hipStream_t stream) {
    const float* x     = (const float*)d_in[0];
    const float* wgt   = (const float*)d_in[1];
    // d_in[2] = bias: mathematically cancels under BN (and is zeros) — unused
    const float* gamma = (const float*)d_in[3];
    const float* beta  = (const float*)d_in[4];
    float* out = (float*)d_out;

    float* stats = (float*)d_ws;                                 // 512 floats
    float* ss    = (float*)((char*)d_ws + 2048);                 // 512 floats
    __hip_bfloat16* y = (__hip_bfloat16*)((char*)d_ws + 4096);   // 25.69M bf16

    k0_zero<<<1, 512, 0, stream>>>(stats);
    k1_conv<<<dim3(4, HH, BB), 256, 0, stream>>>(x, wgt, y, stats);
    k2_finalize<<<1, 256, 0, stream>>>(stats, gamma, beta, ss);
    k3_norm<<<(NPIX*CC)/(256*8), 256, 0, stream>>>(y, ss, out);
}

// Round 2
// 258.156 us; speedup vs baseline: 1.1191x; 1.1191x over previous
//
#include <hip/hip_runtime.h>
#include <hip/hip_bf16.h>

#define BB 32
#define HH 56
#define WW 56
#define CC 256
#define NPIX (BB*HH*WW)   // 100352
#define EPS 1e-5f

typedef short bf16x8 __attribute__((ext_vector_type(8)));   // 8 bf16 = 4 VGPRs
typedef float f32x4  __attribute__((ext_vector_type(4)));

__device__ __forceinline__ unsigned short f2bf(float f) {
    __hip_bfloat16 h = __float2bfloat16(f);
    return *reinterpret_cast<unsigned short*>(&h);
}

// ws layout:
//   float stats[512]   : byte 0      (sum[256], sumsq[256])
//   float ss[512]      : byte 2048   (scale[256], shift[256])
//   bf16  y[B*H*W*256] : byte 4096   (51.4 MB)

__global__ void k0_zero(float* stats) { stats[threadIdx.x] = 0.f; }

// Grouped conv via bf16 MFMA. Block: one group-pair (16 out-ch), one 8-row
// band, one batch image. K packed as [g0 taps0-8 +pad][g1 taps0-8 +pad] = 160
// -> 5 x mfma_f32_16x16x32_bf16 with block-diagonal B (zeros off-diag).
// A fragment = 8 contiguous bf16 (one tap's 8 in-ch) read straight from the
// LDS x-tile -- no im2col materialization.
__global__ __launch_bounds__(256) void k1_conv(
    const float* __restrict__ x, const float* __restrict__ wgt,
    __hip_bfloat16* __restrict__ y, float* __restrict__ stats)
{
    __shared__ unsigned short xt[10*58*16];   // bf16 x tile [row][col][16ch] 18.6 KB
    __shared__ unsigned short wb[16*160];     // B-frag-major weights [n][kk]  5.1 KB
    __shared__ float bsum[16], bsq[16];

    const int gp = blockIdx.x;      // group pair 0..15 (channels gp*16..+16)
    const int hb = blockIdx.y;      // 8-row band 0..6
    const int b  = blockIdx.z;
    const int t  = threadIdx.x;
    const int h0 = hb * 8;

    if (t < 16) { bsum[t] = 0.f; bsq[t] = 0.f; }

    // ---- stage x tile: rows h0-1..h0+8, cols -1..56, 16 ch, fp32 -> bf16
    for (int i = t; i < 10*58*4; i += 256) {
        int ci4 = i & 3;
        int cq  = i >> 2;
        int col = cq % 58;
        int row = cq / 58;
        int hh  = h0 - 1 + row;
        int wc  = col - 1;
        float4 v = make_float4(0.f, 0.f, 0.f, 0.f);
        if ((unsigned)hh < HH && (unsigned)wc < WW)
            v = *(const float4*)(x + (((size_t)(b*HH + hh)*WW + wc)*CC + gp*16 + ci4*4));
        ushort4 s;
        s.x = f2bf(v.x); s.y = f2bf(v.y); s.z = f2bf(v.z); s.w = f2bf(v.w);
        *(ushort4*)(xt + (row*58 + col)*16 + ci4*4) = s;
    }

    // ---- stage weights, B-fragment-major: wb[n*160 + kk], kk = g*80+tap*8+ci
    for (int i = t; i < 16*160; i += 256) {
        int n  = i / 160;
        int kk = i - n*160;
        int g  = kk >= 80;
        int r  = kk - g*80;
        int tap = r >> 3;
        int ci  = r & 7;
        unsigned short val = 0;
        if (tap < 9 && (n >> 3) == g)
            val = f2bf(wgt[(tap*8 + ci)*CC + gp*16 + n]);
        wb[i] = val;
    }
    __syncthreads();

    const int lane = t & 63;
    const int rp   = t >> 6;              // wave id = row-pair 0..3
    const int n    = lane & 15;           // B col / C col (local out-ch)
    const int q    = lane >> 4;           // quad
    const int m    = lane & 15;           // A row (pixel in 2x8 tile)
    const int rowr = rp*2 + (m >> 3);     // tile row of A pixel (0..7)
    const int colb = m & 7;               // tile col of A pixel within 8-col tile

    // B fragments (held in regs across the whole pixel loop)
    bf16x8 bfrag[5];
    #pragma unroll
    for (int s = 0; s < 5; ++s)
        bfrag[s] = *(const bf16x8*)(wb + n*160 + s*32 + q*8);

    // A-fragment LDS element offsets per K-step (this lane's octet -> tap,g)
    int aoff[5];
    #pragma unroll
    for (int s = 0; s < 5; ++s) {
        int o  = s*4 + q;                 // octet 0..19
        int g  = (o >= 10);
        int tp = o - g*10;
        if (tp == 9) tp = 0;              // pad octet: B is zero there, addr dontcare
        int dh = tp / 3, dw = tp - dh*3;
        aoff[s] = ((rowr + 1 - 1 + dh)*58 + colb + dw)*16 + g*8;
    }

    const int hq = q >> 1;                // C: row-in-pair
    const int wq = (q & 1) * 4;           // C: col base within 8
    float lsum = 0.f, lsq = 0.f;

    for (int ct = 0; ct < 7; ++ct) {      // 7 col-tiles of 8 pixels
        f32x4 acc = {0.f, 0.f, 0.f, 0.f};
        #pragma unroll
        for (int s = 0; s < 5; ++s) {
            bf16x8 af = *(const bf16x8*)(xt + aoff[s] + ct*128);
            acc = __builtin_amdgcn_mfma_f32_16x16x32_bf16(af, bfrag[s], acc, 0, 0, 0);
        }
        const int h = h0 + rp*2 + hq;
        const size_t base = (((size_t)(b*HH + h))*WW + ct*8 + wq)*CC + gp*16 + n;
        #pragma unroll
        for (int i = 0; i < 4; ++i) {
            float v = acc[i];
            y[base + (size_t)i*CC] = __float2bfloat16(v);
            lsum += v;
            lsq  += v * v;
        }
    }

    atomicAdd(&bsum[n], lsum);
    atomicAdd(&bsq[n],  lsq);
    __syncthreads();
    if (t < 16) {
        atomicAdd(&stats[gp*16 + t],       bsum[t]);
        atomicAdd(&stats[256 + gp*16 + t], bsq[t]);
    }
}

__global__ void k2_finalize(const float* __restrict__ stats,
                            const float* __restrict__ gamma,
                            const float* __restrict__ beta,
                            float* __restrict__ ss)
{
    int c = threadIdx.x;
    float inv_n = 1.f / (float)NPIX;
    float mean = stats[c] * inv_n;
    float var  = stats[256 + c] * inv_n - mean * mean;
    float scale = gamma[c] * rsqrtf(var + EPS);
    ss[c]       = scale;
    ss[256 + c] = beta[c] - mean * scale;   // conv bias cancels under BN
}

// Normalize+ReLU. Each thread owns a fixed channel-octet (scale/shift in
// registers -- no LDS, no bank conflicts), loops over 16 pixels.
__global__ __launch_bounds__(256) void k3_norm(
    const __hip_bfloat16* __restrict__ y, const float* __restrict__ ss,
    float* __restrict__ out)
{
    const int t   = threadIdx.x;
    const int oct = t & 31;               // channel octet
    const int pr  = t >> 5;               // pixel sub-index 0..7
    const int c0  = oct * 8;

    float4 sc0 = *(const float4*)(ss + c0);
    float4 sc1 = *(const float4*)(ss + c0 + 4);
    float4 sh0 = *(const float4*)(ss + 256 + c0);
    float4 sh1 = *(const float4*)(ss + 256 + c0 + 4);

    const uint4* yv = (const uint4*)y;
    float4* ov = (float4*)out;
    const int px0 = blockIdx.x * 128 + pr;

    #pragma unroll
    for (int i = 0; i < 16; ++i) {
        const int px = px0 + i*8;
        uint4 d = yv[(size_t)px*32 + oct];

        float f0 = __uint_as_float((d.x & 0xffffu) << 16);
        float f1 = __uint_as_float(d.x & 0xffff0000u);
        float f2 = __uint_as_float((d.y & 0xffffu) << 16);
        float f3 = __uint_as_float(d.y & 0xffff0000u);
        float f4 = __uint_as_float((d.z & 0xffffu) << 16);
        float f5 = __uint_as_float(d.z & 0xffff0000u);
        float f6 = __uint_as_float((d.w & 0xffffu) << 16);
        float f7 = __uint_as_float(d.w & 0xffff0000u);

        float4 o0, o1;
        o0.x = fmaxf(0.f, f0 * sc0.x + sh0.x);
        o0.y = fmaxf(0.f, f1 * sc0.y + sh0.y);
        o0.z = fmaxf(0.f, f2 * sc0.z + sh0.z);
        o0.w = fmaxf(0.f, f3 * sc0.w + sh0.w);
        o1.x = fmaxf(0.f, f4 * sc1.x + sh1.x);
        o1.y = fmaxf(0.f, f5 * sc1.y + sh1.y);
        o1.z = fmaxf(0.f, f6 * sc1.z + sh1.z);
        o1.w = fmaxf(0.f, f7 * sc1.w + sh1.w);

        ov[(size_t)px*64 + oct*2]     = o0;
        ov[(size_t)px*64 + oct*2 + 1] = o1;
    }
}

extern "C" void kernel_launch(void* const* d_in, const int* in_sizes, int n_in,
                              void* d_out, int out_size, void* d_ws, size_t ws_size,
                              hipStream_t stream) {
    const float* x     = (const float*)d_in[0];
    const float* wgt   = (const float*)d_in[1];
    // d_in[2] = conv bias: cancels exactly under BN mean-subtraction -- unused
    const float* gamma = (const float*)d_in[3];
    const float* beta  = (const float*)d_in[4];
    float* out = (float*)d_out;

    float* stats = (float*)d_ws;                                 // 512 floats
    float* ss    = (float*)((char*)d_ws + 2048);                 // 512 floats
    __hip_bfloat16* y = (__hip_bfloat16*)((char*)d_ws + 4096);   // 25.69M bf16

    k0_zero<<<1, 512, 0, stream>>>(stats);
    k1_conv<<<dim3(16, 7, BB), 256, 0, stream>>>(x, wgt, y, stats);
    k2_finalize<<<1, 256, 0, stream>>>(stats, gamma, beta, ss);
    k3_norm<<<NPIX/128, 256, 0, stream>>>(y, ss, out);
}

// Round 3
// 249.952 us; speedup vs baseline: 1.1558x; 1.0328x over previous
//
#include <hip/hip_runtime.h>
#include <hip/hip_bf16.h>

#define BB 32
#define HH 56
#define WW 56
#define CC 256
#define NPIX (BB*HH*WW)   // 100352
#define EPS 1e-5f

typedef short bf16x8 __attribute__((ext_vector_type(8)));   // 8 bf16 = 4 VGPRs
typedef float f32x4  __attribute__((ext_vector_type(4)));

__device__ __forceinline__ unsigned short f2bf(float f) {
    __hip_bfloat16 h = __float2bfloat16(f);
    return *reinterpret_cast<unsigned short*>(&h);
}

// ws layout:
//   float stats[512]   : byte 0      (sum[256], sumsq[256])
//   float ss[512]      : byte 2048   (scale[256], shift[256])
//   bf16  y[B*H*W*256] : byte 4096   (51.4 MB)

__global__ void k0_zero(float* stats) { stats[threadIdx.x] = 0.f; }

// Grouped conv via bf16 MFMA. Block: one group-pair (16 out-ch), one 8-row
// band, one batch image. K packed [g0 taps + pad][g1 taps + pad] = 160
// -> 5 x mfma_f32_16x16x32_bf16 with block-diagonal B.
// Per-pixel LDS stride padded 16->24 shorts (48B = 12 banks): the 16 lanes of
// each K-step octet read hit every bank-quad exactly twice -> 2-way (free).
__global__ __launch_bounds__(256) void k1_conv(
    const float* __restrict__ x, const float* __restrict__ wgt,
    __hip_bfloat16* __restrict__ y, float* __restrict__ stats)
{
    __shared__ unsigned short xt[10*58*24];   // bf16 tile, padded stride (27.2 KB)
    __shared__ unsigned short wb[16*160];     // B-frag-major weights (5 KB)
    __shared__ float bsum[16], bsq[16];

    const int gp = blockIdx.x;      // group pair 0..15 (channels gp*16..+16)
    const int hb = blockIdx.y;      // 8-row band 0..6
    const int b  = blockIdx.z;
    const int t  = threadIdx.x;
    const int h0 = hb * 8;

    if (t < 16) { bsum[t] = 0.f; bsq[t] = 0.f; }

    // ---- stage x tile (rows h0-1..h0+8, cols -1..56, 16 ch), fully unrolled:
    // all global loads issued before any conversion (batched vmcnt).
    float4 v[10];
    int    off[10];
    #pragma unroll
    for (int j = 0; j < 10; ++j) {
        const int i   = j*256 + t;        // < 2320 valid (only j=9 partial)
        const int ci4 = i & 3;
        const int cq  = i >> 2;
        const int row = cq / 58;          // const divisor -> magic mul
        const int col = cq - row*58;
        const int hh  = h0 - 1 + row;
        const int wc  = col - 1;
        off[j] = (row*58 + col)*24 + ci4*4;
        v[j] = make_float4(0.f, 0.f, 0.f, 0.f);
        if (i < 2320 && (unsigned)hh < HH && (unsigned)wc < WW)
            v[j] = *(const float4*)(x + (((size_t)(b*HH + hh)*WW + wc)*CC + gp*16 + ci4*4));
    }
    // ---- stage weights (no integer division; compile-time predicates)
    {
        const int n  = t >> 4;            // 0..15 local out-ch
        const int k0 = t & 15;
        #pragma unroll
        for (int j = 0; j < 10; ++j) {
            const int kk  = k0 + j*16;    // 0..159
            const int g   = (kk >= 80);
            const int r   = kk - g*80;
            const int tap = r >> 3, ci = r & 7;
            unsigned short val = 0;
            if (tap < 9 && (n >> 3) == g)
                val = f2bf(wgt[(tap*8 + ci)*CC + gp*16 + n]);
            wb[n*160 + kk] = val;
        }
    }
    #pragma unroll
    for (int j = 0; j < 10; ++j) {
        if (j*256 + t < 2320) {
            ushort4 s;
            s.x = f2bf(v[j].x); s.y = f2bf(v[j].y);
            s.z = f2bf(v[j].z); s.w = f2bf(v[j].w);
            *(ushort4*)(xt + off[j]) = s;
        }
    }
    __syncthreads();

    const int lane = t & 63;
    const int rp   = t >> 6;              // wave id = row-pair 0..3
    const int n    = lane & 15;           // B col (local out-ch)
    const int q    = lane >> 4;           // quad
    const int m    = lane & 15;           // A row (pixel in 2x8 tile)
    const int rowr = rp*2 + (m >> 3);     // tile row of A pixel (0..7)
    const int colb = m & 7;               // tile col within 8-col tile

    // B fragments in regs for the whole pixel loop
    bf16x8 bfrag[5];
    #pragma unroll
    for (int s = 0; s < 5; ++s)
        bfrag[s] = *(const bf16x8*)(wb + n*160 + s*32 + q*8);

    // A-fragment LDS offsets per K-step (lane octet -> tap,g)
    int aoff[5];
    #pragma unroll
    for (int s = 0; s < 5; ++s) {
        int o  = s*4 + q;                 // octet 0..19
        int g  = (o >= 10);
        int tp = o - g*10;
        if (tp == 9) tp = 0;              // pad octet: B is zero, addr dontcare
        int dh = tp / 3, dw = tp - dh*3;
        aoff[s] = ((rowr + dh)*58 + colb + dw)*24 + g*8;
    }

    const int hq = q >> 1;                // C: row-in-pair
    const int wq = (q & 1) * 4;           // C: col base within 8
    float lsum = 0.f, lsq = 0.f;

    #pragma unroll 2
    for (int ct = 0; ct < 7; ++ct) {      // 7 col-tiles of 8 pixels
        f32x4 acc = {0.f, 0.f, 0.f, 0.f};
        #pragma unroll
        for (int s = 0; s < 5; ++s) {
            bf16x8 af = *(const bf16x8*)(xt + aoff[s] + ct*192);
            acc = __builtin_amdgcn_mfma_f32_16x16x32_bf16(af, bfrag[s], acc, 0, 0, 0);
        }
        const int h = h0 + rp*2 + hq;
        const size_t base = (((size_t)(b*HH + h))*WW + ct*8 + wq)*CC + gp*16 + n;
        #pragma unroll
        for (int i = 0; i < 4; ++i) {
            float vv = acc[i];
            y[base + (size_t)i*CC] = __float2bfloat16(vv);
            lsum += vv;
            lsq  += vv * vv;
        }
    }

    atomicAdd(&bsum[n], lsum);
    atomicAdd(&bsq[n],  lsq);
    __syncthreads();
    if (t < 16) {
        atomicAdd(&stats[gp*16 + t],       bsum[t]);
        atomicAdd(&stats[256 + gp*16 + t], bsq[t]);
    }
}

__global__ void k2_finalize(const float* __restrict__ stats,
                            const float* __restrict__ gamma,
                            const float* __restrict__ beta,
                            float* __restrict__ ss)
{
    int c = threadIdx.x;
    float inv_n = 1.f / (float)NPIX;
    float mean = stats[c] * inv_n;
    float var  = stats[256 + c] * inv_n - mean * mean;
    float scale = gamma[c] * rsqrtf(var + EPS);
    ss[c]       = scale;
    ss[256 + c] = beta[c] - mean * scale;   // conv bias cancels under BN
}

// Normalize+ReLU. Fixed channel-octet per thread (scale/shift in regs, no
// LDS). 4 rounds per thread, 3136 blocks -> many independent memory streams.
__global__ __launch_bounds__(256) void k3_norm(
    const __hip_bfloat16* __restrict__ y, const float* __restrict__ ss,
    float* __restrict__ out)
{
    const int t   = threadIdx.x;
    const int oct = t & 31;               // channel octet
    const int pr  = t >> 5;               // pixel sub-index 0..7
    const int c0  = oct * 8;

    float4 sc0 = *(const float4*)(ss + c0);
    float4 sc1 = *(const float4*)(ss + c0 + 4);
    float4 sh0 = *(const float4*)(ss + 256 + c0);
    float4 sh1 = *(const float4*)(ss + 256 + c0 + 4);

    const uint4* yv = (const uint4*)y;
    float4* ov = (float4*)out;
    const int px0 = blockIdx.x * 32 + pr;

    uint4 d[4];
    #pragma unroll
    for (int i = 0; i < 4; ++i)
        d[i] = yv[(size_t)(px0 + i*8)*32 + oct];

    #pragma unroll
    for (int i = 0; i < 4; ++i) {
        const int px = px0 + i*8;
        float f0 = __uint_as_float((d[i].x & 0xffffu) << 16);
        float f1 = __uint_as_float(d[i].x & 0xffff0000u);
        float f2 = __uint_as_float((d[i].y & 0xffffu) << 16);
        float f3 = __uint_as_float(d[i].y & 0xffff0000u);
        float f4 = __uint_as_float((d[i].z & 0xffffu) << 16);
        float f5 = __uint_as_float(d[i].z & 0xffff0000u);
        float f6 = __uint_as_float((d[i].w & 0xffffu) << 16);
        float f7 = __uint_as_float(d[i].w & 0xffff0000u);

        float4 o0, o1;
        o0.x = fmaxf(0.f, f0 * sc0.x + sh0.x);
        o0.y = fmaxf(0.f, f1 * sc0.y + sh0.y);
        o0.z = fmaxf(0.f, f2 * sc0.z + sh0.z);
        o0.w = fmaxf(0.f, f3 * sc0.w + sh0.w);
        o1.x = fmaxf(0.f, f4 * sc1.x + sh1.x);
        o1.y = fmaxf(0.f, f5 * sc1.y + sh1.y);
        o1.z = fmaxf(0.f, f6 * sc1.z + sh1.z);
        o1.w = fmaxf(0.f, f7 * sc1.w + sh1.w);

        ov[(size_t)px*64 + oct*2]     = o0;
        ov[(size_t)px*64 + oct*2 + 1] = o1;
    }
}

extern "C" void kernel_launch(void* const* d_in, const int* in_sizes, int n_in,
                              void* d_out, int out_size, void* d_ws, size_t ws_size,
                              hipStream_t stream) {
    const float* x     = (const float*)d_in[0];
    const float* wgt   = (const float*)d_in[1];
    // d_in[2] = conv bias: cancels exactly under BN mean-subtraction -- unused
    const float* gamma = (const float*)d_in[3];
    const float* beta  = (const float*)d_in[4];
    float* out = (float*)d_out;

    float* stats = (float*)d_ws;                                 // 512 floats
    float* ss    = (float*)((char*)d_ws + 2048);                 // 512 floats
    __hip_bfloat16* y = (__hip_bfloat16*)((char*)d_ws + 4096);   // 25.69M bf16

    k0_zero<<<1, 512, 0, stream>>>(stats);
    k1_conv<<<dim3(16, 7, BB), 256, 0, stream>>>(x, wgt, y, stats);
    k2_finalize<<<1, 256, 0, stream>>>(stats, gamma, beta, ss);
    k3_norm<<<NPIX/32, 256, 0, stream>>>(y, ss, out);
}